// Round 1
// baseline (1999.177 us; speedup 1.0000x reference)
//
#include <hip/hip_runtime.h>
#include <hip/hip_bf16.h>

#define NTOK 16384
#define HD 1024
#define NE 8
#define FD 4096
#define BM 128
#define MAXTILES 264  // max sum ceil(cnt_e/128) = 256 + 7, padded

typedef short short8 __attribute__((ext_vector_type(8)));
typedef unsigned short ushort8 __attribute__((ext_vector_type(8)));
typedef float f32x4 __attribute__((ext_vector_type(4)));

__device__ __forceinline__ unsigned short f2bf(float f) {
    unsigned int u = __builtin_bit_cast(unsigned int, f);
    u += 0x7fffu + ((u >> 16) & 1u);   // RNE
    return (unsigned short)(u >> 16);
}

__global__ void zero16_kernel(uint4* __restrict__ p, int n16) {
    int t = blockIdx.x * 256 + threadIdx.x;
    if (t < n16) p[t] = make_uint4(0u, 0u, 0u, 0u);
}

// ---------------- Router: fp32 logits, top-2, renormalized weights ----------
__global__ __launch_bounds__(256)
void router_kernel(const float* __restrict__ X, const float* __restrict__ Wr,
                   float* __restrict__ logits_out, int* __restrict__ te,
                   float* __restrict__ tw) {
    int wave = threadIdx.x >> 6, lane = threadIdx.x & 63;
    int token = blockIdx.x * 4 + wave;
    const float* x = X + (size_t)token * HD;
    float acc[NE];
#pragma unroll
    for (int e = 0; e < NE; e++) acc[e] = 0.f;
#pragma unroll 4
    for (int j = 0; j < HD / 64; j++) {
        int i = lane + 64 * j;
        float xv = x[i];
        float4 w0 = *(const float4*)(Wr + (size_t)i * NE);
        float4 w1 = *(const float4*)(Wr + (size_t)i * NE + 4);
        acc[0] += xv * w0.x; acc[1] += xv * w0.y;
        acc[2] += xv * w0.z; acc[3] += xv * w0.w;
        acc[4] += xv * w1.x; acc[5] += xv * w1.y;
        acc[6] += xv * w1.z; acc[7] += xv * w1.w;
    }
#pragma unroll
    for (int off = 32; off >= 1; off >>= 1)
#pragma unroll
        for (int e = 0; e < NE; e++)
            acc[e] += __shfl_xor(acc[e], off, 64);
    if (lane < NE) logits_out[(size_t)token * NE + lane] = acc[lane];
    if (lane == 0) {
        int i1 = 0;
#pragma unroll
        for (int e = 1; e < NE; e++) if (acc[e] > acc[i1]) i1 = e;
        int i2 = (i1 == 0) ? 1 : 0;
#pragma unroll
        for (int e = 0; e < NE; e++) if (e != i1 && acc[e] > acc[i2]) i2 = e;
        // top_w renormalized: p1/(p1+p2) = 1/(1+exp(l2-l1))
        float w0 = 1.f / (1.f + __expf(acc[i2] - acc[i1]));
        te[token * 2] = i1; te[token * 2 + 1] = i2;
        tw[token * 2] = w0; tw[token * 2 + 1] = 1.f - w0;
    }
}

// ---------------- Histogram / scan / scatter (bucket by expert) -------------
__global__ void hist_kernel(const int* __restrict__ te, int* __restrict__ meta) {
    __shared__ int c[NE];
    int t = threadIdx.x;
    if (t < NE) c[t] = 0;
    __syncthreads();
    int tok = blockIdx.x * 256 + t;
    atomicAdd(&c[te[tok * 2]], 1);
    atomicAdd(&c[te[tok * 2 + 1]], 1);
    __syncthreads();
    if (t < NE) atomicAdd(&meta[t], c[t]);
}

__global__ void scan_kernel(int* __restrict__ meta) {
    if (threadIdx.x == 0) {
        int* counts = meta;       // [0..7]
        int* offs   = meta + 8;   // [8..16]
        int* tb     = meta + 17;  // [17..25]
        int* cur    = meta + 26;  // [26..33]
        offs[0] = 0; tb[0] = 0;
        for (int e = 0; e < NE; e++) {
            offs[e + 1] = offs[e] + counts[e];
            tb[e + 1] = tb[e] + (counts[e] + BM - 1) / BM;
            cur[e] = offs[e];
        }
    }
}

__global__ void scatter_kernel(const int* __restrict__ te, const float* __restrict__ tw,
                               int* __restrict__ meta, int* __restrict__ tok_ids,
                               float* __restrict__ aw) {
    __shared__ int c[NE];
    __shared__ int base[NE];
    int t = threadIdx.x;
    if (t < NE) c[t] = 0;
    __syncthreads();
    int tok = blockIdx.x * 256 + t;
    int e0 = te[tok * 2], e1 = te[tok * 2 + 1];
    int i0 = atomicAdd(&c[e0], 1);
    int i1 = atomicAdd(&c[e1], 1);
    __syncthreads();
    if (t < NE) base[t] = atomicAdd(&meta[26 + t], c[t]);
    __syncthreads();
    int p0 = base[e0] + i0, p1 = base[e1] + i1;
    tok_ids[p0] = tok; aw[p0] = tw[tok * 2];
    tok_ids[p1] = tok; aw[p1] = tw[tok * 2 + 1];
}

// ---------------- fp32 -> bf16 converts ------------------------------------
__global__ void convert_x_kernel(const float* __restrict__ in, unsigned short* __restrict__ out) {
    size_t t = (size_t)blockIdx.x * 256 + threadIdx.x;
    float4 a = ((const float4*)in)[t * 2];
    float4 b = ((const float4*)in)[t * 2 + 1];
    ushort8 o;
    o[0] = f2bf(a.x); o[1] = f2bf(a.y); o[2] = f2bf(a.z); o[3] = f2bf(a.w);
    o[4] = f2bf(b.x); o[5] = f2bf(b.y); o[6] = f2bf(b.z); o[7] = f2bf(b.w);
    *(ushort8*)(out + t * 8) = o;
}

// in [E][R][C] fp32 -> out [E][C][R] bf16 (64x64 tiles)
__global__ __launch_bounds__(256)
void transpose_convert_kernel(const float* __restrict__ in, unsigned short* __restrict__ out,
                              int R, int C) {
    __shared__ float tile[64][65];
    int e = blockIdx.z;
    int c0 = blockIdx.x * 64, r0 = blockIdx.y * 64;
    const float* src = in + (size_t)e * R * C;
    unsigned short* dst = out + (size_t)e * R * C;
    int t = threadIdx.x;
#pragma unroll
    for (int i = 0; i < 4; i++) {
        int idx = t + i * 256;               // 0..1023
        int row = idx >> 4, c4 = (idx & 15) * 4;
        float4 v = *(const float4*)(src + (size_t)(r0 + row) * C + c0 + c4);
        tile[row][c4] = v.x; tile[row][c4 + 1] = v.y;
        tile[row][c4 + 2] = v.z; tile[row][c4 + 3] = v.w;
    }
    __syncthreads();
#pragma unroll
    for (int i = 0; i < 2; i++) {
        int idx = t + i * 256;               // 0..511
        int c = idx >> 3, rc = (idx & 7) * 8;
        ushort8 o;
#pragma unroll
        for (int j = 0; j < 8; j++) o[j] = f2bf(tile[rc + j][c]);
        *(ushort8*)(dst + (size_t)(c0 + c) * R + r0 + rc) = o;
    }
}

// ---------------- Pass A: h = silu(Xg @ W1) * (Xg @ W3), grouped ------------
__global__ __launch_bounds__(256, 2)
void moe_gemm_a(const unsigned short* __restrict__ Xb,
                const unsigned short* __restrict__ W1t,   // [E][F][H]
                const unsigned short* __restrict__ W3t,   // [E][F][H]
                unsigned short* __restrict__ hbuf,        // [32768][FC]
                const int* __restrict__ meta,
                const int* __restrict__ tok_ids,
                int f0, int FC) {
    const int* counts = meta;
    const int* offs = meta + 8;
    const int* tb = meta + 17;
    int bx = blockIdx.x;
    if (bx >= tb[NE]) return;
    int e = 0;
    while (bx >= tb[e + 1]) e++;
    int tIdx = bx - tb[e];
    int rowsBase = offs[e] + tIdx * BM;
    int rowsInTile = counts[e] - tIdx * BM;
    if (rowsInTile > BM) rowsInTile = BM;
    int n0 = blockIdx.y * 64;                // chunk-local F col base

    __shared__ unsigned short As[128 * 40];  // stride 40 shorts (80B, 16B-aligned)
    __shared__ unsigned short B1s[64 * 40];
    __shared__ unsigned short B3s[64 * 40];

    int t = threadIdx.x;
    int wave = t >> 6, lane = t & 63, q = lane >> 4, m = lane & 15;
    int pos8 = (t & 3) * 8;
    int r0 = t >> 2;                         // 0..63
    int rta = min(r0, rowsInTile - 1);
    int rtb = min(64 + r0, rowsInTile - 1);
    int tok_a = tok_ids[rowsBase + rta];
    int tok_b = tok_ids[rowsBase + rtb];
    const unsigned short* apA = Xb + (size_t)tok_a * HD + pos8;
    const unsigned short* apB = Xb + (size_t)tok_b * HD + pos8;
    const unsigned short* bp1 = W1t + ((size_t)e * FD + f0 + n0 + r0) * HD + pos8;
    const unsigned short* bp3 = W3t + ((size_t)e * FD + f0 + n0 + r0) * HD + pos8;
    unsigned short* lwA = As + r0 * 40 + pos8;
    unsigned short* lwB = As + (64 + r0) * 40 + pos8;
    unsigned short* lw1 = B1s + r0 * 40 + pos8;
    unsigned short* lw3 = B3s + r0 * 40 + pos8;

    f32x4 accg[2][4], accu[2][4];
#pragma unroll
    for (int ri = 0; ri < 2; ri++)
#pragma unroll
        for (int ci = 0; ci < 4; ci++) {
            accg[ri][ci] = (f32x4){0.f, 0.f, 0.f, 0.f};
            accu[ri][ci] = (f32x4){0.f, 0.f, 0.f, 0.f};
        }

    for (int kt = 0; kt < HD; kt += 32) {
        uint4 vA = *(const uint4*)(apA + kt);
        uint4 vB = *(const uint4*)(apB + kt);
        uint4 v1 = *(const uint4*)(bp1 + kt);
        uint4 v3 = *(const uint4*)(bp3 + kt);
        __syncthreads();
        *(uint4*)lwA = vA; *(uint4*)lwB = vB;
        *(uint4*)lw1 = v1; *(uint4*)lw3 = v3;
        __syncthreads();
        short8 af[2], b1f[4], b3f[4];
#pragma unroll
        for (int ri = 0; ri < 2; ri++)
            af[ri] = *(const short8*)(As + (wave * 32 + ri * 16 + m) * 40 + q * 8);
#pragma unroll
        for (int ci = 0; ci < 4; ci++) {
            b1f[ci] = *(const short8*)(B1s + (ci * 16 + m) * 40 + q * 8);
            b3f[ci] = *(const short8*)(B3s + (ci * 16 + m) * 40 + q * 8);
        }
#pragma unroll
        for (int ri = 0; ri < 2; ri++)
#pragma unroll
            for (int ci = 0; ci < 4; ci++) {
                accg[ri][ci] = __builtin_amdgcn_mfma_f32_16x16x32_bf16(af[ri], b1f[ci], accg[ri][ci], 0, 0, 0);
                accu[ri][ci] = __builtin_amdgcn_mfma_f32_16x16x32_bf16(af[ri], b3f[ci], accu[ri][ci], 0, 0, 0);
            }
    }
    // epilogue: SwiGLU, store bf16 h.  C/D layout: col=lane&15, row=q*4+reg
#pragma unroll
    for (int ri = 0; ri < 2; ri++)
#pragma unroll
        for (int ci = 0; ci < 4; ci++)
#pragma unroll
            for (int r = 0; r < 4; r++) {
                int rl = wave * 32 + ri * 16 + q * 4 + r;
                if (rl < rowsInTile) {
                    float g = accg[ri][ci][r], u = accu[ri][ci][r];
                    float hv = g * u / (1.f + __expf(-g));
                    hbuf[(size_t)(rowsBase + rl) * FC + n0 + ci * 16 + m] = f2bf(hv);
                }
            }
}

// ---------------- Pass B: out += w * (h @ W2), grouped, atomic --------------
__global__ __launch_bounds__(256, 2)
void moe_gemm_b(const unsigned short* __restrict__ hbuf,  // [32768][FC]
                const unsigned short* __restrict__ W2t,   // [E][H][F]
                float* __restrict__ out,
                const int* __restrict__ meta,
                const int* __restrict__ tok_ids,
                const float* __restrict__ aw,
                int f0, int FC) {
    const int* counts = meta;
    const int* offs = meta + 8;
    const int* tb = meta + 17;
    int bx = blockIdx.x;
    if (bx >= tb[NE]) return;
    int e = 0;
    while (bx >= tb[e + 1]) e++;
    int tIdx = bx - tb[e];
    int rowsBase = offs[e] + tIdx * BM;
    int rowsInTile = counts[e] - tIdx * BM;
    if (rowsInTile > BM) rowsInTile = BM;
    int n0 = blockIdx.y * 128;               // H col base

    __shared__ unsigned short As[128 * 40];
    __shared__ unsigned short Bs[128 * 40];

    int t = threadIdx.x;
    int wave = t >> 6, lane = t & 63, q = lane >> 4, m = lane & 15;
    int wr = (wave >> 1) * 64, wc = (wave & 1) * 64;
    int pos8 = (t & 3) * 8;
    int r0 = t >> 2;                         // 0..63
    int rta = min(r0, rowsInTile - 1);
    int rtb = min(64 + r0, rowsInTile - 1);
    const unsigned short* apA = hbuf + (size_t)(rowsBase + rta) * FC + pos8;
    const unsigned short* apB = hbuf + (size_t)(rowsBase + rtb) * FC + pos8;
    const unsigned short* bpA = W2t + ((size_t)e * HD + n0 + r0) * FD + f0 + pos8;
    const unsigned short* bpB = W2t + ((size_t)e * HD + n0 + 64 + r0) * FD + f0 + pos8;
    unsigned short* lwA = As + r0 * 40 + pos8;
    unsigned short* lwB = As + (64 + r0) * 40 + pos8;
    unsigned short* lwC = Bs + r0 * 40 + pos8;
    unsigned short* lwD = Bs + (64 + r0) * 40 + pos8;

    f32x4 acc[4][4];
#pragma unroll
    for (int ri = 0; ri < 4; ri++)
#pragma unroll
        for (int ci = 0; ci < 4; ci++) acc[ri][ci] = (f32x4){0.f, 0.f, 0.f, 0.f};

    for (int kt = 0; kt < FC; kt += 32) {
        uint4 vA = *(const uint4*)(apA + kt);
        uint4 vB = *(const uint4*)(apB + kt);
        uint4 vC = *(const uint4*)(bpA + kt);
        uint4 vD = *(const uint4*)(bpB + kt);
        __syncthreads();
        *(uint4*)lwA = vA; *(uint4*)lwB = vB;
        *(uint4*)lwC = vC; *(uint4*)lwD = vD;
        __syncthreads();
        short8 af[4], bf[4];
#pragma unroll
        for (int ri = 0; ri < 4; ri++)
            af[ri] = *(const short8*)(As + (wr + ri * 16 + m) * 40 + q * 8);
#pragma unroll
        for (int ci = 0; ci < 4; ci++)
            bf[ci] = *(const short8*)(Bs + (wc + ci * 16 + m) * 40 + q * 8);
#pragma unroll
        for (int ri = 0; ri < 4; ri++)
#pragma unroll
            for (int ci = 0; ci < 4; ci++)
                acc[ri][ci] = __builtin_amdgcn_mfma_f32_16x16x32_bf16(af[ri], bf[ci], acc[ri][ci], 0, 0, 0);
    }
#pragma unroll
    for (int ri = 0; ri < 4; ri++)
#pragma unroll
        for (int ci = 0; ci < 4; ci++)
#pragma unroll
            for (int r = 0; r < 4; r++) {
                int rl = wr + ri * 16 + q * 4 + r;
                if (rl < rowsInTile) {
                    int arow = rowsBase + rl;
                    int tok = tok_ids[arow];
                    float w = aw[arow];
                    atomicAdd(out + (size_t)tok * HD + n0 + wc + ci * 16 + m,
                              acc[ri][ci][r] * w);
                }
            }
}

// ---------------- launch -----------------------------------------------------
extern "C" void kernel_launch(void* const* d_in, const int* in_sizes, int n_in,
                              void* d_out, int out_size, void* d_ws, size_t ws_size,
                              hipStream_t stream) {
    const float* X  = (const float*)d_in[0];
    const float* Wr = (const float*)d_in[1];
    const float* W1 = (const float*)d_in[2];
    const float* W2 = (const float*)d_in[3];
    const float* W3 = (const float*)d_in[4];
    float* out = (float*)d_out;
    float* logits_out = out + (size_t)NTOK * HD;

    char* ws = (char*)d_ws;
    size_t off = 0;
    auto alloc = [&](size_t bytes) -> void* {
        void* p = ws + off;
        off = (off + bytes + 255) & ~(size_t)255;
        return p;
    };
    unsigned short* Xb  = (unsigned short*)alloc((size_t)NTOK * HD * 2);
    unsigned short* W1t = (unsigned short*)alloc((size_t)NE * HD * FD * 2);
    unsigned short* W3t = (unsigned short*)alloc((size_t)NE * HD * FD * 2);
    unsigned short* W2t = (unsigned short*)alloc((size_t)NE * HD * FD * 2);
    int*   tok_ids = (int*)alloc((size_t)NTOK * 2 * 4);
    float* awf     = (float*)alloc((size_t)NTOK * 2 * 4);
    int*   te      = (int*)alloc((size_t)NTOK * 2 * 4);
    float* twf     = (float*)alloc((size_t)NTOK * 2 * 4);
    int*   meta    = (int*)alloc(64 * 4);
    size_t remain = ws_size > off ? ws_size - off : 0;
    int NC = 1;
    while ((size_t)NTOK * 2 * (size_t)(FD / NC) * 2 > remain && NC < 32) NC *= 2;
    int FC = FD / NC;
    unsigned short* hbuf = (unsigned short*)(ws + off);

    // zero out (atomic accumulation target) and meta
    zero16_kernel<<<(NTOK * HD * 4 / 16 + 255) / 256, 256, 0, stream>>>((uint4*)out, NTOK * HD * 4 / 16);
    zero16_kernel<<<1, 256, 0, stream>>>((uint4*)meta, 16);

    router_kernel<<<NTOK / 4, 256, 0, stream>>>(X, Wr, logits_out, te, twf);
    hist_kernel<<<NTOK / 256, 256, 0, stream>>>(te, meta);
    scan_kernel<<<1, 64, 0, stream>>>(meta);
    scatter_kernel<<<NTOK / 256, 256, 0, stream>>>(te, twf, meta, tok_ids, awf);

    convert_x_kernel<<<NTOK * HD / 8 / 256, 256, 0, stream>>>(X, Xb);
    transpose_convert_kernel<<<dim3(FD / 64, HD / 64, NE), 256, 0, stream>>>(W1, W1t, HD, FD);
    transpose_convert_kernel<<<dim3(FD / 64, HD / 64, NE), 256, 0, stream>>>(W3, W3t, HD, FD);
    transpose_convert_kernel<<<dim3(HD / 64, FD / 64, NE), 256, 0, stream>>>(W2, W2t, FD, HD);

    for (int c = 0; c < NC; c++) {
        moe_gemm_a<<<dim3(MAXTILES, FC / 64), 256, 0, stream>>>(Xb, W1t, W3t, hbuf, meta, tok_ids, c * FC, FC);
        moe_gemm_b<<<dim3(MAXTILES, HD / 128), 256, 0, stream>>>(hbuf, W2t, out, meta, tok_ids, awf, c * FC, FC);
    }
}

// Round 2
// 1721.462 us; speedup vs baseline: 1.1613x; 1.1613x over previous
//
#include <hip/hip_runtime.h>
#include <hip/hip_bf16.h>

#define NTOK 16384
#define HD 1024
#define NE 8
#define FD 4096
#define BM 128
#define MAXTILES 264  // max sum ceil(cnt_e/128) = 256 + 7, padded

typedef short short8 __attribute__((ext_vector_type(8)));
typedef unsigned short ushort8 __attribute__((ext_vector_type(8)));
typedef float f32x4 __attribute__((ext_vector_type(4)));

__device__ __forceinline__ unsigned short f2bf(float f) {
    unsigned int u = __builtin_bit_cast(unsigned int, f);
    u += 0x7fffu + ((u >> 16) & 1u);   // RNE
    return (unsigned short)(u >> 16);
}

__global__ void zero16_kernel(uint4* __restrict__ p, int n16) {
    int t = blockIdx.x * 256 + threadIdx.x;
    if (t < n16) p[t] = make_uint4(0u, 0u, 0u, 0u);
}

// ---------------- Router: fp32 logits, top-2, renormalized weights ----------
__global__ __launch_bounds__(256)
void router_kernel(const float* __restrict__ X, const float* __restrict__ Wr,
                   float* __restrict__ logits_out, int* __restrict__ te,
                   float* __restrict__ tw) {
    int wave = threadIdx.x >> 6, lane = threadIdx.x & 63;
    int token = blockIdx.x * 4 + wave;
    const float* x = X + (size_t)token * HD;
    float acc[NE];
#pragma unroll
    for (int e = 0; e < NE; e++) acc[e] = 0.f;
#pragma unroll 4
    for (int j = 0; j < HD / 64; j++) {
        int i = lane + 64 * j;
        float xv = x[i];
        float4 w0 = *(const float4*)(Wr + (size_t)i * NE);
        float4 w1 = *(const float4*)(Wr + (size_t)i * NE + 4);
        acc[0] += xv * w0.x; acc[1] += xv * w0.y;
        acc[2] += xv * w0.z; acc[3] += xv * w0.w;
        acc[4] += xv * w1.x; acc[5] += xv * w1.y;
        acc[6] += xv * w1.z; acc[7] += xv * w1.w;
    }
#pragma unroll
    for (int off = 32; off >= 1; off >>= 1)
#pragma unroll
        for (int e = 0; e < NE; e++)
            acc[e] += __shfl_xor(acc[e], off, 64);
    if (lane < NE) logits_out[(size_t)token * NE + lane] = acc[lane];
    if (lane == 0) {
        int i1 = 0;
#pragma unroll
        for (int e = 1; e < NE; e++) if (acc[e] > acc[i1]) i1 = e;
        int i2 = (i1 == 0) ? 1 : 0;
#pragma unroll
        for (int e = 0; e < NE; e++) if (e != i1 && acc[e] > acc[i2]) i2 = e;
        float w0 = 1.f / (1.f + __expf(acc[i2] - acc[i1]));
        te[token * 2] = i1; te[token * 2 + 1] = i2;
        tw[token * 2] = w0; tw[token * 2 + 1] = 1.f - w0;
    }
}

// ---------------- Histogram / scan / scatter (bucket by expert) -------------
__global__ void hist_kernel(const int* __restrict__ te, int* __restrict__ meta) {
    __shared__ int c[NE];
    int t = threadIdx.x;
    if (t < NE) c[t] = 0;
    __syncthreads();
    int tok = blockIdx.x * 256 + t;
    atomicAdd(&c[te[tok * 2]], 1);
    atomicAdd(&c[te[tok * 2 + 1]], 1);
    __syncthreads();
    if (t < NE) atomicAdd(&meta[t], c[t]);
}

__global__ void scan_kernel(int* __restrict__ meta) {
    if (threadIdx.x == 0) {
        int* counts = meta;       // [0..7]
        int* offs   = meta + 8;   // [8..16]
        int* tb     = meta + 17;  // [17..25]
        int* cur    = meta + 26;  // [26..33]
        offs[0] = 0; tb[0] = 0;
        for (int e = 0; e < NE; e++) {
            offs[e + 1] = offs[e] + counts[e];
            tb[e + 1] = tb[e] + (counts[e] + BM - 1) / BM;
            cur[e] = offs[e];
        }
    }
}

__global__ void scatter_kernel(const int* __restrict__ te, const float* __restrict__ tw,
                               int* __restrict__ meta, int* __restrict__ tok_ids,
                               float* __restrict__ aw) {
    __shared__ int c[NE];
    __shared__ int base[NE];
    int t = threadIdx.x;
    if (t < NE) c[t] = 0;
    __syncthreads();
    int tok = blockIdx.x * 256 + t;
    int e0 = te[tok * 2], e1 = te[tok * 2 + 1];
    int i0 = atomicAdd(&c[e0], 1);
    int i1 = atomicAdd(&c[e1], 1);
    __syncthreads();
    if (t < NE) base[t] = atomicAdd(&meta[26 + t], c[t]);
    __syncthreads();
    int p0 = base[e0] + i0, p1 = base[e1] + i1;
    tok_ids[p0] = tok; aw[p0] = tw[tok * 2];
    tok_ids[p1] = tok; aw[p1] = tw[tok * 2 + 1];
}

// ---------------- fp32 -> bf16 converts ------------------------------------
__global__ void convert_x_kernel(const float* __restrict__ in, unsigned short* __restrict__ out) {
    size_t t = (size_t)blockIdx.x * 256 + threadIdx.x;
    float4 a = ((const float4*)in)[t * 2];
    float4 b = ((const float4*)in)[t * 2 + 1];
    ushort8 o;
    o[0] = f2bf(a.x); o[1] = f2bf(a.y); o[2] = f2bf(a.z); o[3] = f2bf(a.w);
    o[4] = f2bf(b.x); o[5] = f2bf(b.y); o[6] = f2bf(b.z); o[7] = f2bf(b.w);
    *(ushort8*)(out + t * 8) = o;
}

// in [E][R][C] fp32 -> out [E][C][R] bf16 (64x64 tiles)
__global__ __launch_bounds__(256)
void transpose_convert_kernel(const float* __restrict__ in, unsigned short* __restrict__ out,
                              int R, int C) {
    __shared__ float tile[64][65];
    int e = blockIdx.z;
    int c0 = blockIdx.x * 64, r0 = blockIdx.y * 64;
    const float* src = in + (size_t)e * R * C;
    unsigned short* dst = out + (size_t)e * R * C;
    int t = threadIdx.x;
#pragma unroll
    for (int i = 0; i < 4; i++) {
        int idx = t + i * 256;               // 0..1023
        int row = idx >> 4, c4 = (idx & 15) * 4;
        float4 v = *(const float4*)(src + (size_t)(r0 + row) * C + c0 + c4);
        tile[row][c4] = v.x; tile[row][c4 + 1] = v.y;
        tile[row][c4 + 2] = v.z; tile[row][c4 + 3] = v.w;
    }
    __syncthreads();
#pragma unroll
    for (int i = 0; i < 2; i++) {
        int idx = t + i * 256;               // 0..511
        int c = idx >> 3, rc = (idx & 7) * 8;
        ushort8 o;
#pragma unroll
        for (int j = 0; j < 8; j++) o[j] = f2bf(tile[rc + j][c]);
        *(ushort8*)(dst + (size_t)(c0 + c) * R + r0 + rc) = o;
    }
}

// ---------------- Pass A: h = silu(Xg @ W1) * (Xg @ W3), grouped ------------
// Tile: 128 rows x 128 F-cols, dual-matmul (gate+up share A).
// blockIdx.x = F-col block (FASTEST -> adjacent blocks share the A row-tile
// in L2/L3; this is the round-2 fetch fix), blockIdx.y = row tile.
__global__ __launch_bounds__(256, 2)
void moe_gemm_a(const unsigned short* __restrict__ Xb,
                const unsigned short* __restrict__ W1t,   // [E][F][H]
                const unsigned short* __restrict__ W3t,   // [E][F][H]
                unsigned short* __restrict__ hbuf,        // [32768][FC]
                const int* __restrict__ meta,
                const int* __restrict__ tok_ids,
                int f0, int FC) {
    const int* counts = meta;
    const int* offs = meta + 8;
    const int* tb = meta + 17;
    int by = blockIdx.y;
    if (by >= tb[NE]) return;
    int e = 0;
    while (by >= tb[e + 1]) e++;
    int tIdx = by - tb[e];
    int rowsBase = offs[e] + tIdx * BM;
    int rowsInTile = counts[e] - tIdx * BM;
    if (rowsInTile > BM) rowsInTile = BM;
    int n0 = blockIdx.x * 128;               // chunk-local F col base

    __shared__ unsigned short As[128 * 40];  // stride 40 shorts (80B): 2-way-max banks
    __shared__ unsigned short B1s[128 * 40];
    __shared__ unsigned short B3s[128 * 40];

    int t = threadIdx.x;
    int wave = t >> 6, lane = t & 63, q = lane >> 4, m = lane & 15;
    int wr = (wave >> 1) * 64, wc = (wave & 1) * 64;
    int pos8 = (t & 3) * 8;
    int r0 = t >> 2;                         // 0..63
    int rta = min(r0, rowsInTile - 1);
    int rtb = min(64 + r0, rowsInTile - 1);
    const unsigned short* apA = Xb + (size_t)tok_ids[rowsBase + rta] * HD + pos8;
    const unsigned short* apB = Xb + (size_t)tok_ids[rowsBase + rtb] * HD + pos8;
    const unsigned short* bp1a = W1t + ((size_t)e * FD + f0 + n0 + r0) * HD + pos8;
    const unsigned short* bp1b = W1t + ((size_t)e * FD + f0 + n0 + 64 + r0) * HD + pos8;
    const unsigned short* bp3a = W3t + ((size_t)e * FD + f0 + n0 + r0) * HD + pos8;
    const unsigned short* bp3b = W3t + ((size_t)e * FD + f0 + n0 + 64 + r0) * HD + pos8;
    unsigned short* lwA0 = As + r0 * 40 + pos8;
    unsigned short* lwA1 = As + (64 + r0) * 40 + pos8;
    unsigned short* lw10 = B1s + r0 * 40 + pos8;
    unsigned short* lw11 = B1s + (64 + r0) * 40 + pos8;
    unsigned short* lw30 = B3s + r0 * 40 + pos8;
    unsigned short* lw31 = B3s + (64 + r0) * 40 + pos8;

    f32x4 accg[4][4], accu[4][4];
#pragma unroll
    for (int ri = 0; ri < 4; ri++)
#pragma unroll
        for (int ci = 0; ci < 4; ci++) {
            accg[ri][ci] = (f32x4){0.f, 0.f, 0.f, 0.f};
            accu[ri][ci] = (f32x4){0.f, 0.f, 0.f, 0.f};
        }

    for (int kt = 0; kt < HD; kt += 32) {
        uint4 vA0 = *(const uint4*)(apA + kt);
        uint4 vA1 = *(const uint4*)(apB + kt);
        uint4 v10 = *(const uint4*)(bp1a + kt);
        uint4 v11 = *(const uint4*)(bp1b + kt);
        uint4 v30 = *(const uint4*)(bp3a + kt);
        uint4 v31 = *(const uint4*)(bp3b + kt);
        __syncthreads();
        *(uint4*)lwA0 = vA0; *(uint4*)lwA1 = vA1;
        *(uint4*)lw10 = v10; *(uint4*)lw11 = v11;
        *(uint4*)lw30 = v30; *(uint4*)lw31 = v31;
        __syncthreads();
        short8 af[4], b1f[4], b3f[4];
#pragma unroll
        for (int ri = 0; ri < 4; ri++)
            af[ri] = *(const short8*)(As + (wr + ri * 16 + m) * 40 + q * 8);
#pragma unroll
        for (int ci = 0; ci < 4; ci++) {
            b1f[ci] = *(const short8*)(B1s + (wc + ci * 16 + m) * 40 + q * 8);
            b3f[ci] = *(const short8*)(B3s + (wc + ci * 16 + m) * 40 + q * 8);
        }
#pragma unroll
        for (int ri = 0; ri < 4; ri++)
#pragma unroll
            for (int ci = 0; ci < 4; ci++) {
                accg[ri][ci] = __builtin_amdgcn_mfma_f32_16x16x32_bf16(af[ri], b1f[ci], accg[ri][ci], 0, 0, 0);
                accu[ri][ci] = __builtin_amdgcn_mfma_f32_16x16x32_bf16(af[ri], b3f[ci], accu[ri][ci], 0, 0, 0);
            }
    }
    // epilogue: SwiGLU, store bf16 h.  C/D layout: col=lane&15, row=q*4+reg
#pragma unroll
    for (int ri = 0; ri < 4; ri++)
#pragma unroll
        for (int ci = 0; ci < 4; ci++)
#pragma unroll
            for (int r = 0; r < 4; r++) {
                int rl = wr + ri * 16 + q * 4 + r;
                if (rl < rowsInTile) {
                    float g = accg[ri][ci][r], u = accu[ri][ci][r];
                    float hv = g * u / (1.f + __expf(-g));
                    hbuf[(size_t)(rowsBase + rl) * FC + n0 + wc + ci * 16 + m] = f2bf(hv);
                }
            }
}

// ---------------- Pass B: out += w * (h @ W2), grouped, atomic --------------
// blockIdx.x = H-col block (FASTEST -> 8 adjacent blocks share the 1MB hbuf
// row-tile in L2/L3), blockIdx.y = row tile.
__global__ __launch_bounds__(256, 2)
void moe_gemm_b(const unsigned short* __restrict__ hbuf,  // [32768][FC]
                const unsigned short* __restrict__ W2t,   // [E][H][F]
                float* __restrict__ out,
                const int* __restrict__ meta,
                const int* __restrict__ tok_ids,
                const float* __restrict__ aw,
                int f0, int FC) {
    const int* counts = meta;
    const int* offs = meta + 8;
    const int* tb = meta + 17;
    int by = blockIdx.y;
    if (by >= tb[NE]) return;
    int e = 0;
    while (by >= tb[e + 1]) e++;
    int tIdx = by - tb[e];
    int rowsBase = offs[e] + tIdx * BM;
    int rowsInTile = counts[e] - tIdx * BM;
    if (rowsInTile > BM) rowsInTile = BM;
    int n0 = blockIdx.x * 128;               // H col base

    __shared__ unsigned short As[128 * 40];
    __shared__ unsigned short Bs[128 * 40];

    int t = threadIdx.x;
    int wave = t >> 6, lane = t & 63, q = lane >> 4, m = lane & 15;
    int wr = (wave >> 1) * 64, wc = (wave & 1) * 64;
    int pos8 = (t & 3) * 8;
    int r0 = t >> 2;                         // 0..63
    int rta = min(r0, rowsInTile - 1);
    int rtb = min(64 + r0, rowsInTile - 1);
    const unsigned short* apA = hbuf + (size_t)(rowsBase + rta) * FC + pos8;
    const unsigned short* apB = hbuf + (size_t)(rowsBase + rtb) * FC + pos8;
    const unsigned short* bpA = W2t + ((size_t)e * HD + n0 + r0) * FD + f0 + pos8;
    const unsigned short* bpB = W2t + ((size_t)e * HD + n0 + 64 + r0) * FD + f0 + pos8;
    unsigned short* lwA = As + r0 * 40 + pos8;
    unsigned short* lwB = As + (64 + r0) * 40 + pos8;
    unsigned short* lwC = Bs + r0 * 40 + pos8;
    unsigned short* lwD = Bs + (64 + r0) * 40 + pos8;

    f32x4 acc[4][4];
#pragma unroll
    for (int ri = 0; ri < 4; ri++)
#pragma unroll
        for (int ci = 0; ci < 4; ci++) acc[ri][ci] = (f32x4){0.f, 0.f, 0.f, 0.f};

    for (int kt = 0; kt < FC; kt += 32) {
        uint4 vA = *(const uint4*)(apA + kt);
        uint4 vB = *(const uint4*)(apB + kt);
        uint4 vC = *(const uint4*)(bpA + kt);
        uint4 vD = *(const uint4*)(bpB + kt);
        __syncthreads();
        *(uint4*)lwA = vA; *(uint4*)lwB = vB;
        *(uint4*)lwC = vC; *(uint4*)lwD = vD;
        __syncthreads();
        short8 af[4], bf[4];
#pragma unroll
        for (int ri = 0; ri < 4; ri++)
            af[ri] = *(const short8*)(As + (wr + ri * 16 + m) * 40 + q * 8);
#pragma unroll
        for (int ci = 0; ci < 4; ci++)
            bf[ci] = *(const short8*)(Bs + (wc + ci * 16 + m) * 40 + q * 8);
#pragma unroll
        for (int ri = 0; ri < 4; ri++)
#pragma unroll
            for (int ci = 0; ci < 4; ci++)
                acc[ri][ci] = __builtin_amdgcn_mfma_f32_16x16x32_bf16(af[ri], bf[ci], acc[ri][ci], 0, 0, 0);
    }
#pragma unroll
    for (int ri = 0; ri < 4; ri++)
#pragma unroll
        for (int ci = 0; ci < 4; ci++)
#pragma unroll
            for (int r = 0; r < 4; r++) {
                int rl = wr + ri * 16 + q * 4 + r;
                if (rl < rowsInTile) {
                    int arow = rowsBase + rl;
                    int tok = tok_ids[arow];
                    float w = aw[arow];
                    atomicAdd(out + (size_t)tok * HD + n0 + wc + ci * 16 + m,
                              acc[ri][ci][r] * w);
                }
            }
}

// ---------------- launch -----------------------------------------------------
extern "C" void kernel_launch(void* const* d_in, const int* in_sizes, int n_in,
                              void* d_out, int out_size, void* d_ws, size_t ws_size,
                              hipStream_t stream) {
    const float* X  = (const float*)d_in[0];
    const float* Wr = (const float*)d_in[1];
    const float* W1 = (const float*)d_in[2];
    const float* W2 = (const float*)d_in[3];
    const float* W3 = (const float*)d_in[4];
    float* out = (float*)d_out;
    float* logits_out = out + (size_t)NTOK * HD;

    char* ws = (char*)d_ws;
    size_t off = 0;
    auto alloc = [&](size_t bytes) -> void* {
        void* p = ws + off;
        off = (off + bytes + 255) & ~(size_t)255;
        return p;
    };
    unsigned short* Xb  = (unsigned short*)alloc((size_t)NTOK * HD * 2);
    unsigned short* W1t = (unsigned short*)alloc((size_t)NE * HD * FD * 2);
    unsigned short* W3t = (unsigned short*)alloc((size_t)NE * HD * FD * 2);
    unsigned short* W2t = (unsigned short*)alloc((size_t)NE * HD * FD * 2);
    int*   tok_ids = (int*)alloc((size_t)NTOK * 2 * 4);
    float* awf     = (float*)alloc((size_t)NTOK * 2 * 4);
    int*   te      = (int*)alloc((size_t)NTOK * 2 * 4);
    float* twf     = (float*)alloc((size_t)NTOK * 2 * 4);
    int*   meta    = (int*)alloc(64 * 4);
    size_t remain = ws_size > off ? ws_size - off : 0;
    int NC = 1;
    while ((size_t)NTOK * 2 * (size_t)(FD / NC) * 2 > remain && NC < 32) NC *= 2;
    int FC = FD / NC;
    unsigned short* hbuf = (unsigned short*)(ws + off);

    // zero out (atomic accumulation target) and meta
    zero16_kernel<<<(NTOK * HD * 4 / 16 + 255) / 256, 256, 0, stream>>>((uint4*)out, NTOK * HD * 4 / 16);
    zero16_kernel<<<1, 256, 0, stream>>>((uint4*)meta, 16);

    router_kernel<<<NTOK / 4, 256, 0, stream>>>(X, Wr, logits_out, te, twf);
    hist_kernel<<<NTOK / 256, 256, 0, stream>>>(te, meta);
    scan_kernel<<<1, 64, 0, stream>>>(meta);
    scatter_kernel<<<NTOK / 256, 256, 0, stream>>>(te, twf, meta, tok_ids, awf);

    convert_x_kernel<<<NTOK * HD / 8 / 256, 256, 0, stream>>>(X, Xb);
    transpose_convert_kernel<<<dim3(FD / 64, HD / 64, NE), 256, 0, stream>>>(W1, W1t, HD, FD);
    transpose_convert_kernel<<<dim3(FD / 64, HD / 64, NE), 256, 0, stream>>>(W3, W3t, HD, FD);
    transpose_convert_kernel<<<dim3(HD / 64, FD / 64, NE), 256, 0, stream>>>(W2, W2t, FD, HD);

    for (int c = 0; c < NC; c++) {
        moe_gemm_a<<<dim3(FC / 128, MAXTILES), 256, 0, stream>>>(Xb, W1t, W3t, hbuf, meta, tok_ids, c * FC, FC);
        moe_gemm_b<<<dim3(HD / 128, MAXTILES), 256, 0, stream>>>(hbuf, W2t, out, meta, tok_ids, awf, c * FC, FC);
    }
}